// Round 8
// baseline (17794.504 us; speedup 1.0000x reference)
//
#include <hip/hip_runtime.h>

// ---------------------------------------------------------------------------
// DeepMemoryLevel (ATLAS-style). B=2 S=1024 D=2048 M=512 P=1024 H=2048
// CHUNK=32 NC=32, tokens N=2048.
// Round 8: NS5 GEMMs moved to 128x128 4-wave m97-style kernel:
// global_load_lds (no wave ds_writes), XOR-swizzled LDS via pre-swizzled
// global source (rule #21), split-K=2 on square GEMMs to fill 256 blocks,
// bf16 partials in the dead Xn buffer + 2 combine kernels.
// Chunk path keeps the barrier-free 1-wave 64x64 kernel.
// ---------------------------------------------------------------------------

typedef unsigned short us;
typedef __attribute__((ext_vector_type(8))) short s16x8;
typedef __attribute__((ext_vector_type(8))) unsigned short u16x8;
typedef __attribute__((ext_vector_type(4))) float f32x4;

#define MKP 72

__device__ __forceinline__ float gelu_f(float x) {
  return 0.5f * x * (1.0f + erff(x * 0.70710678118654752f));
}
__device__ __forceinline__ float gelu_grad_f(float x) {
  float cdf = 0.5f * (1.0f + erff(x * 0.70710678118654752f));
  float pdf = 0.3989422804014327f * expf(-0.5f * x * x);
  return cdf + x * pdf;
}
__device__ __forceinline__ float sigmoid_f(float x) { return 1.0f / (1.0f + expf(-x)); }

__device__ __forceinline__ us f2bf(float f) {
  union { float f; unsigned u; } v; v.f = f;
  unsigned r = (v.u + 0x7FFFu + ((v.u >> 16) & 1u)) >> 16;
  return (us)r;
}
__device__ __forceinline__ float bf2f(us h) {
  union { unsigned u; float f; } v; v.u = ((unsigned)h) << 16;
  return v.f;
}
// token-major index n -> chunk-major row
__device__ __forceinline__ int cm_map(int n) {
  return ((n & 1023) >> 5) * 64 + (n >> 10) * 32 + (n & 31);
}

__device__ __forceinline__ void gload16(const us* g, us* l) {
  __builtin_amdgcn_global_load_lds(
      (const __attribute__((address_space(1))) void*)g,
      (__attribute__((address_space(3))) void*)l, 16, 0, 0);
}

__device__ __forceinline__ float block_reduce_sum(float v, float* red) {
  int t = threadIdx.x;
  red[t] = v; __syncthreads();
  for (int s = blockDim.x >> 1; s > 0; s >>= 1) {
    if (t < s) red[t] += red[t + s];
    __syncthreads();
  }
  float r = red[0];
  __syncthreads();
  return r;
}

// ---------------- NS 128x128 4-wave MFMA GEMM (global_load_lds + swizzle) ---
// C[M,N](+split) = A @ Bsrc^T ; A row-major M x K (lda), Bsrc row-major N x K.
// grid.z = batch*KS; z -> (b = z/KS, s = z%KS); block computes K-range
// [s*K/KS, (s+1)*K/KS). EPI 0: C us = acc (partial). EPI 6: C us =
// c1*acc + c2*bf(E[row,col]).
// LDS tiles [128][64] bf16 linear (16KB each); content XOR-swizzled on 16B
// units: LDS[r][u] = G[r][u ^ (r&7)] (achieved by pre-swizzling the global
// source address; global_load_lds dest = wave base + lane*16).
template<int KS, int EPI>
__global__ __launch_bounds__(256)
void ns_k(const us* __restrict__ Aq, const us* __restrict__ Bq,
          us* __restrict__ Cq, const us* __restrict__ Eq,
          int M, int N, int K, int lda, int ldb, int ldc, int lde,
          float c1, float c2, long sA, long sB, long sC, long sE) {
  __shared__ __align__(16) us As[128 * 64];
  __shared__ __align__(16) us Bs[128 * 64];
  const int bz = blockIdx.z;
  const int bb = bz / KS, ss = bz % KS;
  const int KH = K / KS;
  const us* A = Aq + (size_t)bb * sA + (size_t)ss * KH;
  const us* B = Bq + (size_t)bb * sB + (size_t)ss * KH;
  us* C = Cq + (size_t)bz * sC;
  const int t = threadIdx.x;
  const int wave = t >> 6, lane = t & 63;
  const int m0 = blockIdx.y * 128, n0 = blockIdx.x * 128;
  const int wm = (wave >> 1) * 64, wn = (wave & 1) * 64;
  const int l15 = lane & 15, l4 = lane >> 4;
  const int lr = lane >> 3;   // row within 8-row group
  const int lu = lane & 7;    // 16B unit within row

  f32x4 acc[4][4];
#pragma unroll
  for (int i = 0; i < 4; ++i)
#pragma unroll
    for (int j = 0; j < 4; ++j) acc[i][j] = (f32x4){0.f, 0.f, 0.f, 0.f};

  for (int k0 = 0; k0 < KH; k0 += 64) {
    // stage A,B tiles: 4 calls each per wave; lane l covers LDS bytes
    // base+16l = row (grp*8 + l>>3), unit (l&7). Source unit pre-swizzled.
#pragma unroll
    for (int j = 0; j < 4; ++j) {
      int r = (wave * 4 + j) * 8 + lr;
      int u = lu ^ (r & 7);
      gload16(A + (size_t)(m0 + r) * lda + k0 + u * 8, As + (wave * 4 + j) * 512);
      gload16(B + (size_t)(n0 + r) * ldb + k0 + u * 8, Bs + (wave * 4 + j) * 512);
    }
    __syncthreads();   // drains vmcnt -> staged tiles visible
#pragma unroll
    for (int ks = 0; ks < 2; ++ks) {
      s16x8 af[4], bf[4];
#pragma unroll
      for (int mi = 0; mi < 4; ++mi) {
        int ra = wm + mi * 16 + l15;
        int cu = (ks * 4 + l4) ^ (ra & 7);
        af[mi] = *(const s16x8*)&As[ra * 64 + cu * 8];
      }
#pragma unroll
      for (int ni = 0; ni < 4; ++ni) {
        int rb = wn + ni * 16 + l15;
        int cu = (ks * 4 + l4) ^ (rb & 7);
        bf[ni] = *(const s16x8*)&Bs[rb * 64 + cu * 8];
      }
#pragma unroll
      for (int mi = 0; mi < 4; ++mi)
#pragma unroll
        for (int ni = 0; ni < 4; ++ni)
          acc[mi][ni] = __builtin_amdgcn_mfma_f32_16x16x32_bf16(af[mi], bf[ni], acc[mi][ni], 0, 0, 0);
    }
    __syncthreads();   // protect LDS before next stage overwrites
  }

#pragma unroll
  for (int mi = 0; mi < 4; ++mi) {
#pragma unroll
    for (int i = 0; i < 4; ++i) {
      int row = m0 + wm + mi * 16 + l4 * 4 + i;
#pragma unroll
      for (int ni = 0; ni < 4; ++ni) {
        int col = n0 + wn + ni * 16 + l15;
        float v = acc[mi][ni][i];
        if constexpr (EPI == 0) {
          C[(size_t)row * ldc + col] = f2bf(v);
        } else {
          const us* E = Eq + (size_t)bb * sE;
          C[(size_t)row * ldc + col] =
              f2bf(c1 * v + c2 * bf2f(E[(size_t)row * lde + col]));
        }
      }
    }
  }
}

template<int KS, int EPI>
static void nsg(hipStream_t st, const us* A, const us* B, us* C, const us* E,
                int M, int N, int K, int lda, int ldb, int ldc, int lde,
                float c1, float c2, long sA, long sB, long sC, long sE, int batch) {
  dim3 g(N / 128, M / 128, batch * KS), b(256);
  hipLaunchKernelGGL((ns_k<KS, EPI>), g, b, 0, st, A, B, C, E,
                     M, N, K, lda, ldb, ldc, lde, c1, c2, sA, sB, sC, sE);
}

// combine split-K bf16 partials: Ab[b][j] = P[b*2][j] + P[b*2+1][j]
__global__ __launch_bounds__(256) void combA_k(const u16x8* __restrict__ P,
                                               u16x8* __restrict__ Ab) {
  int i = blockIdx.x * 256 + threadIdx.x;          // over 2M/8 = 262144
  int b = i >> 17, j = i & 131071;
  u16x8 p0 = P[(size_t)(b * 2) * 131072 + j];
  u16x8 p1 = P[(size_t)(b * 2 + 1) * 131072 + j];
  u16x8 o;
#pragma unroll
  for (int q = 0; q < 8; ++q) o[q] = f2bf(bf2f(p0[q]) + bf2f(p1[q]));
  Ab[i] = o;
}

// Bb[b][j] = nsc*(P0+P1) + nsb*Ab
__global__ __launch_bounds__(256) void combB_k(const u16x8* __restrict__ P,
                                               const u16x8* __restrict__ Ab,
                                               u16x8* __restrict__ Bb,
                                               float nsb, float nsc) {
  int i = blockIdx.x * 256 + threadIdx.x;
  int b = i >> 17, j = i & 131071;
  u16x8 p0 = P[(size_t)(b * 2) * 131072 + j];
  u16x8 p1 = P[(size_t)(b * 2 + 1) * 131072 + j];
  u16x8 ab = Ab[i];
  u16x8 o;
#pragma unroll
  for (int q = 0; q < 8; ++q)
    o[q] = f2bf(nsc * (bf2f(p0[q]) + bf2f(p1[q])) + nsb * bf2f(ab[q]));
  Bb[i] = o;
}

// ---------------- 1-wave 64x64 bf16 MFMA GEMM (barrier-free, chunk path) ----
// C[M,N] = A @ Bsrc^T, Bsrc row-major N x K (ldb).
// TA=0: A row-major M x K (lda). TA=1: A row-major K x M (lda = M-stride).
// DUAL: block rows [64,128) read from A2 (row-64). AG: global A row = cm_map.
// EPI: 5  C us = acc
//      7  C f32 = acc
//      8  C us = gelu(acc); if m0>=64: C2 f32[(m-64),n] = gelu'(acc)
//      9  C us: m0<64 -> acc ; else -> 2*(acc - E_f32[(m-64),n])
//      13 C f32 = acc * E_f32[m,n]
//      14 C f32 = cp[3ci+1]*C_old - cp[3ci]*acc
//      15 C f32 = FX[m,n] + acc*OG[m]
//      17 C f32, row scattered to cm_map(m)
template<int EPI, int TA, int DUAL, int AG>
__global__ __launch_bounds__(64)
void mg_k(const us* __restrict__ Aq, const us* __restrict__ A2,
          const us* __restrict__ Bq, void* __restrict__ Cq,
          void* __restrict__ C2, const void* __restrict__ Eq,
          const float* __restrict__ FX, const float* __restrict__ OG,
          const float* __restrict__ cp, int cidx,
          int M, int N, int K, int lda, int ldb, int ldc, int lde,
          float c1, float c2, long sA, long sB, long sC, long sE) {
  __shared__ __align__(16) us As[64 * MKP];
  __shared__ __align__(16) us Bs[64 * MKP];
  const int bz = blockIdx.z;
  const us* A = Aq + (size_t)bz * sA;
  const us* B = Bq + (size_t)bz * sB;
  const int t = threadIdx.x;
  const int m0 = blockIdx.y * 64, n0 = blockIdx.x * 64;
  if constexpr (DUAL) { if (m0 >= 64) A = A2; }
  const int mA0 = DUAL ? (m0 & 63) : m0;
  const int l15 = t & 15, l4 = t >> 4;

  f32x4 acc[4][4];
#pragma unroll
  for (int i = 0; i < 4; ++i)
#pragma unroll
    for (int j = 0; j < 4; ++j) acc[i][j] = (f32x4){0.f, 0.f, 0.f, 0.f};

  const int srw = t >> 3;          // 0..7 base row / k
  const int sck = (t & 7) * 8;     // 0..56 col chunk

  u16x8 ra[8], rb[8];
  auto LDA = [&](int k0) {
#pragma unroll
    for (int p = 0; p < 8; ++p) {
      if constexpr (TA == 0) {
        int row = srw + p * 8;
        int srow;
        if constexpr (AG) srow = cm_map(m0 + row); else srow = mA0 + row;
        ra[p] = *(const u16x8*)(A + (size_t)srow * lda + k0 + sck);
      } else {
        ra[p] = *(const u16x8*)(A + (size_t)(k0 + srw + p * 8) * lda + mA0 + sck);
      }
    }
  };
  auto LDB = [&](int k0) {
#pragma unroll
    for (int p = 0; p < 8; ++p)
      rb[p] = *(const u16x8*)(B + (size_t)(n0 + srw + p * 8) * ldb + k0 + sck);
  };

  LDA(0); LDB(0);
  for (int k0 = 0; k0 < K; k0 += 64) {
    if constexpr (TA == 0) {
#pragma unroll
      for (int p = 0; p < 8; ++p)
        *(u16x8*)&As[(srw + p * 8) * MKP + sck] = ra[p];
    } else {
#pragma unroll
      for (int p = 0; p < 8; ++p) {
        int kk = srw + p * 8;
#pragma unroll
        for (int j = 0; j < 8; ++j) As[(sck + j) * MKP + kk] = ra[p][j];
      }
    }
#pragma unroll
    for (int p = 0; p < 8; ++p)
      *(u16x8*)&Bs[(srw + p * 8) * MKP + sck] = rb[p];
    if (k0 + 64 < K) { LDA(k0 + 64); LDB(k0 + 64); }
#pragma unroll
    for (int ks = 0; ks < 2; ++ks) {
      s16x8 af[4], bf[4];
#pragma unroll
      for (int mi = 0; mi < 4; ++mi)
        af[mi] = *(const s16x8*)&As[(mi * 16 + l15) * MKP + ks * 32 + l4 * 8];
#pragma unroll
      for (int ni = 0; ni < 4; ++ni)
        bf[ni] = *(const s16x8*)&Bs[(ni * 16 + l15) * MKP + ks * 32 + l4 * 8];
#pragma unroll
      for (int mi = 0; mi < 4; ++mi)
#pragma unroll
        for (int ni = 0; ni < 4; ++ni)
          acc[mi][ni] = __builtin_amdgcn_mfma_f32_16x16x32_bf16(af[mi], bf[ni], acc[mi][ni], 0, 0, 0);
    }
  }

#pragma unroll
  for (int mi = 0; mi < 4; ++mi) {
#pragma unroll
    for (int i = 0; i < 4; ++i) {
      int grow = m0 + mi * 16 + l4 * 4 + i;
#pragma unroll
      for (int ni = 0; ni < 4; ++ni) {
        int col = n0 + ni * 16 + l15;
        float v = acc[mi][ni][i];
        if constexpr (EPI == 5) {
          ((us*)Cq + bz * sC)[(size_t)grow * ldc + col] = f2bf(v);
        } else if constexpr (EPI == 7) {
          ((float*)Cq)[(size_t)grow * ldc + col] = v;
        } else if constexpr (EPI == 8) {
          ((us*)Cq)[(size_t)grow * ldc + col] = f2bf(gelu_f(v));
          if (m0 >= 64)
            ((float*)C2)[(size_t)(grow - 64) * ldc + col] = gelu_grad_f(v);
        } else if constexpr (EPI == 9) {
          if (m0 < 64)
            ((us*)Cq)[(size_t)grow * ldc + col] = f2bf(v);
          else
            ((us*)Cq)[(size_t)grow * ldc + col] =
                f2bf(2.0f * (v - ((const float*)Eq)[(size_t)(grow - 64) * lde + col]));
        } else if constexpr (EPI == 13) {
          ((float*)Cq)[(size_t)grow * ldc + col] =
              v * ((const float*)Eq)[(size_t)grow * lde + col];
        } else if constexpr (EPI == 14) {
          float* C = (float*)Cq;
          float old = C[(size_t)grow * ldc + col];
          C[(size_t)grow * ldc + col] = cp[cidx * 3 + 1] * old - cp[cidx * 3 + 0] * v;
        } else if constexpr (EPI == 15) {
          ((float*)Cq)[(size_t)grow * ldc + col] =
              FX[(size_t)grow * ldc + col] + v * OG[grow];
        } else if constexpr (EPI == 17) {
          int crow = cm_map(grow);
          ((float*)Cq)[(size_t)crow * ldc + col] = v;
        }
      }
    }
  }
}

template<int EPI, int TA = 0, int DUAL = 0, int AG = 0>
static void mg(hipStream_t st, const us* A, const us* A2, const us* B,
               void* C, void* C2, const void* E,
               const float* FX, const float* OG, const float* cp, int cidx,
               int M, int N, int K, int lda, int ldb, int ldc, int lde,
               float c1, float c2, long sA, long sB, long sC, long sE, int batch) {
  dim3 g(N / 64, M / 64, batch), b(64);
  hipLaunchKernelGGL((mg_k<EPI, TA, DUAL, AG>), g, b, 0, st, A, A2, B, C, C2, E,
                     FX, OG, cp, cidx, M, N, K, lda, ldb, ldc, lde, c1, c2, sA, sB, sC, sE);
}

// ---------------- conversions ----------------

__global__ __launch_bounds__(256) void conv_k(const float* __restrict__ in,
                                              us* __restrict__ out, int n) {
  for (int i = blockIdx.x * 256 + threadIdx.x; i < n; i += gridDim.x * 256)
    out[i] = f2bf(in[i]);
}

// out_bf16[C x R] = (in_f32[R x C])^T
__global__ void tconv_k(const float* __restrict__ in, us* __restrict__ out, int R, int C) {
  __shared__ float tile[32][33];
  int c0 = blockIdx.x * 32, r0 = blockIdx.y * 32;
  int tx = threadIdx.x, ty = threadIdx.y;
#pragma unroll
  for (int j = 0; j < 4; ++j)
    tile[ty + 8 * j][tx] = in[(size_t)(r0 + ty + 8 * j) * C + c0 + tx];
  __syncthreads();
#pragma unroll
  for (int j = 0; j < 4; ++j)
    out[(size_t)(c0 + ty + 8 * j) * R + r0 + tx] = f2bf(tile[tx][ty + 8 * j]);
}

// ---------------- elementwise / reductions ----------------

__global__ __launch_bounds__(256) void polynorm2_k(const float* __restrict__ lin,
                                                   us* __restrict__ outp) {
  __shared__ float red[256];
  int n = blockIdx.x, t = threadIdx.x;
  int rowp = cm_map(n);
  float s = 0.f;
  for (int f = t; f < 512; f += 256) { float v = lin[(size_t)n * 512 + f]; s += v * v; }
  float tot = block_reduce_sum(s, red);
  float sc = 1.0f / fmaxf(sqrtf(tot), 1e-12f);
  const float is2 = 0.70710678118654752f;
  for (int f = t; f < 512; f += 256) {
    float v = lin[(size_t)n * 512 + f] * sc;
    outp[(size_t)rowp * 1024 + f] = f2bf(v * is2);
    outp[(size_t)rowp * 1024 + 512 + f] = f2bf(v * v * is2);
  }
}

__global__ __launch_bounds__(256) void gates_k(const float* __restrict__ x,
    const float* __restrict__ wlr, const float* __restrict__ blr,
    const float* __restrict__ wmom, const float* __restrict__ bmom,
    const float* __restrict__ wdec, const float* __restrict__ bdec,
    const float* __restrict__ wgate, const float* __restrict__ bgate,
    float* __restrict__ lrv, float* __restrict__ momv,
    float* __restrict__ decv, float* __restrict__ og) {
  __shared__ float red[256];
  int n = blockIdx.x, t = threadIdx.x;
  float s0 = 0.f, s1 = 0.f, s2 = 0.f, s3 = 0.f;
  for (int d = t; d < 2048; d += 256) {
    float xv = x[(size_t)n * 2048 + d];
    s0 += xv * wlr[d]; s1 += xv * wmom[d]; s2 += xv * wdec[d]; s3 += xv * wgate[d];
  }
  float r0 = block_reduce_sum(s0, red);
  float r1 = block_reduce_sum(s1, red);
  float r2 = block_reduce_sum(s2, red);
  float r3 = block_reduce_sum(s3, red);
  if (t == 0) {
    lrv[n] = sigmoid_f(r0 + blr[0]);
    momv[n] = sigmoid_f(r1 + bmom[0]);
    decv[n] = sigmoid_f(r2 + bdec[0]);
    og[n] = sigmoid_f(r3 + bgate[0]);
  }
}

__global__ void chunk_means_k(const float* __restrict__ lrv, const float* __restrict__ momv,
                              const float* __restrict__ decv, float* __restrict__ cp) {
  int c = blockIdx.x, t = threadIdx.x;  // 64 threads
  int n = ((t >> 5) << 10) + c * 32 + (t & 31);
  float a = lrv[n], b = momv[n], d = decv[n];
  for (int off = 32; off > 0; off >>= 1) {
    a += __shfl_down(a, off);
    b += __shfl_down(b, off);
    d += __shfl_down(d, off);
  }
  if (t == 0) {
    cp[c * 3 + 0] = a * (1.f / 64.f);
    cp[c * 3 + 1] = b * (1.f / 64.f);
    cp[c * 3 + 2] = d * (1.f / 64.f);
  }
}

__global__ __launch_bounds__(256) void sampnorm2_k(const us* __restrict__ kp_b,
                                                   const float* __restrict__ dh,
                                                   const us* __restrict__ hab,
                                                   const us* __restrict__ pr,
                                                   float* __restrict__ w0inv,
                                                   float* __restrict__ w1inv, int c) {
  __shared__ float red[256];
  int i = blockIdx.x, t = threadIdx.x;
  int row = c * 64 + i;
  float sk = 0.f, sr = 0.f, sdh = 0.f, sa = 0.f;
  for (int p = t; p < 1024; p += 256) {
    float v = bf2f(kp_b[(size_t)row * 1024 + p]); sk += v * v;
    v = bf2f(pr[(size_t)(64 + i) * 1024 + p]); sr += v * v;
  }
  for (int h = t; h < 2048; h += 256) {
    float v = dh[(size_t)i * 2048 + h]; sdh += v * v;
    v = bf2f(hab[(size_t)(64 + i) * 2048 + h]); sa += v * v;
  }
  float tk = block_reduce_sum(sk, red);
  float tdh = block_reduce_sum(sdh, red);
  float ta = block_reduce_sum(sa, red);
  float tr = block_reduce_sum(sr, red);
  if (t == 0) {
    float n0 = fmaxf(sqrtf(tk) * sqrtf(tdh), 1e-8f);
    w0inv[i] = 1.0f / (64.0f * fmaxf(n0 * 0.1f, 1.0f));
    float n1 = fmaxf(sqrtf(ta) * sqrtf(tr), 1e-8f);
    w1inv[i] = 1.0f / (64.0f * fmaxf(n1 * 0.1f, 1.0f));
  }
}

template<int INF32>
__global__ void wtrans_k(const void* __restrict__ in, const float* __restrict__ w,
                         us* __restrict__ out, int C, int ldin) {
  __shared__ float tile[32][33];
  int c0 = blockIdx.x * 32, r0 = blockIdx.y * 32;
  int tx = threadIdx.x, ty = threadIdx.y;
#pragma unroll
  for (int j = 0; j < 4; ++j) {
    int r = r0 + ty + 8 * j, cc = c0 + tx;
    float v;
    if constexpr (INF32) v = ((const float*)in)[(size_t)r * ldin + cc];
    else v = bf2f(((const us*)in)[(size_t)r * ldin + cc]);
    tile[ty + 8 * j][tx] = v * w[r];
  }
  __syncthreads();
#pragma unroll
  for (int j = 0; j < 4; ++j)
    out[(size_t)(c0 + ty + 8 * j) * 64 + r0 + tx] = f2bf(tile[tx][ty + 8 * j]);
}

__global__ __launch_bounds__(256) void frob2_k(const float* __restrict__ s0,
                                               const float* __restrict__ s1, int n,
                                               float* __restrict__ parts) {
  __shared__ float red[256];
  const float* s = blockIdx.z ? s1 : s0;
  float acc = 0.f;
  for (int i = blockIdx.x * 256 + threadIdx.x; i < n; i += gridDim.x * 256) {
    float v = s[i]; acc += v * v;
  }
  float r = block_reduce_sum(acc, red);
  if (threadIdx.x == 0) parts[blockIdx.z * 256 + blockIdx.x] = r;
}

__global__ __launch_bounds__(256) void frob_fin2_k(const float* __restrict__ parts,
                                                   float* __restrict__ inv) {
  __shared__ float red[256];
  float r = block_reduce_sum(parts[blockIdx.x * 256 + threadIdx.x], red);
  if (threadIdx.x == 0) inv[blockIdx.x] = 1.0f / (sqrtf(r) + 1e-7f);
}

__global__ void scale_dual_k(const float* __restrict__ in, us* __restrict__ outS,
                             us* __restrict__ outT, const float* __restrict__ inv,
                             int R, int C) {
  __shared__ float tile[32][33];
  float s = *inv;
  int c0 = blockIdx.x * 32, r0 = blockIdx.y * 32;
  int tx = threadIdx.x, ty = threadIdx.y;
#pragma unroll
  for (int j = 0; j < 4; ++j) {
    float v = in[(size_t)(r0 + ty + 8 * j) * C + c0 + tx];
    tile[ty + 8 * j][tx] = v;
    outS[(size_t)(r0 + ty + 8 * j) * C + c0 + tx] = f2bf(v * s);
  }
  __syncthreads();
#pragma unroll
  for (int j = 0; j < 4; ++j)
    outT[(size_t)(c0 + ty + 8 * j) * R + r0 + tx] = f2bf(tile[tx][ty + 8 * j] * s);
}

__global__ void tbf_k(const us* __restrict__ in, us* __restrict__ out) {
  __shared__ us tile[32][33];
  size_t bo = (size_t)blockIdx.z * 2097152;
  int c0 = blockIdx.x * 32, r0 = blockIdx.y * 32;
  int tx = threadIdx.x, ty = threadIdx.y;
#pragma unroll
  for (int j = 0; j < 4; ++j)
    tile[ty + 8 * j][tx] = in[bo + (size_t)(r0 + ty + 8 * j) * 2048 + c0 + tx];
  __syncthreads();
#pragma unroll
  for (int j = 0; j < 4; ++j)
    out[bo + (size_t)(c0 + ty + 8 * j) * 1024 + r0 + tx] = tile[tx][ty + 8 * j];
}

__global__ void wupd0_k(float* __restrict__ W0, const us* __restrict__ X,
                        us* __restrict__ W0bT, const float* __restrict__ cp, int c) {
  __shared__ float tl[32][33];
  float lr = cp[c * 3 + 0], om = 1.0f - cp[c * 3 + 2];
  int c0 = blockIdx.x * 32, r0 = blockIdx.y * 32;
  int tx = threadIdx.x, ty = threadIdx.y;
#pragma unroll
  for (int j = 0; j < 4; ++j) {
    int r = r0 + ty + 8 * j, h = c0 + tx;
    size_t idx = (size_t)r * 2048 + h;
    float v = om * W0[idx] + lr * bf2f(X[idx]);
    W0[idx] = v;
    tl[ty + 8 * j][tx] = v;
  }
  __syncthreads();
#pragma unroll
  for (int j = 0; j < 4; ++j)
    W0bT[(size_t)(c0 + ty + 8 * j) * 1024 + r0 + tx] = f2bf(tl[tx][ty + 8 * j]);
}

__global__ void wupd1_k(float* __restrict__ W1, const us* __restrict__ X2,
                        us* __restrict__ W1b, us* __restrict__ W1bT,
                        const float* __restrict__ cp, int c) {
  __shared__ float tX[32][33];
  __shared__ float t2[32][33];
  float lr = cp[c * 3 + 0], om = 1.0f - cp[c * 3 + 2];
  int h0 = blockIdx.x * 32, p0 = blockIdx.y * 32;
  int tx = threadIdx.x, ty = threadIdx.y;
#pragma unroll
  for (int j = 0; j < 4; ++j)
    tX[ty + 8 * j][tx] = bf2f(X2[(size_t)(p0 + ty + 8 * j) * 2048 + h0 + tx]);
  __syncthreads();
#pragma unroll
  for (int j = 0; j < 4; ++j) {
    int h = h0 + ty + 8 * j, p = p0 + tx;
    size_t idx = (size_t)h * 1024 + p;
    float v = om * W1[idx] + lr * tX[tx][ty + 8 * j];
    W1[idx] = v;
    W1b[idx] = f2bf(v);
    t2[tx][ty + 8 * j] = v;
  }
  __syncthreads();
#pragma unroll
  for (int j = 0; j < 4; ++j)
    W1bT[(size_t)(p0 + ty + 8 * j) * 2048 + h0 + tx] = f2bf(t2[ty + 8 * j][tx]);
}

// ---------------- host ----------------

extern "C" void kernel_launch(void* const* d_in, const int* in_sizes, int n_in,
                              void* d_out, int out_size, void* d_ws, size_t ws_size,
                              hipStream_t stream) {
  const float* x = (const float*)d_in[0];
  const float* Wk = (const float*)d_in[1];
  const float* Wv = (const float*)d_in[2];
  const float* Wq = (const float*)d_in[3];
  const float* Wout = (const float*)d_in[4];
  const float* w_lr = (const float*)d_in[5];
  const float* b_lr = (const float*)d_in[6];
  const float* w_mom = (const float*)d_in[7];
  const float* b_mom = (const float*)d_in[8];
  const float* w_dec = (const float*)d_in[9];
  const float* b_dec = (const float*)d_in[10];
  const float* w_gate = (const float*)d_in[11];
  const float* b_gate = (const float*)d_in[12];
  const float* Wmem0 = (const float*)d_in[13];
  const float* Wmem1 = (const float*)d_in[14];
  const float* Wmemout = (const float*)d_in[15];
  const float* Wvexp = (const float*)d_in[16];
  float* out = (float*)d_out;
  (void)n_in; (void)in_sizes; (void)out_size;

  const long F = 1048576;
  const long BIG = 2097152;
  const long SB2 = 2097152, SB1 = 1048576;
  float* ws = (float*)d_ws;
  if (ws_size < (size_t)25043464 * sizeof(float)) return;

  us* kp_b   = (us*)ws;               // [0,1F)
  us* qp_b   = (us*)(ws + F);         // [1,2)
  float* vexp = ws + 2 * F;           // [2,4)
  float* W0  = ws + 4 * F;            // [4,6)
  float* W1  = ws + 6 * F;            // [6,8)
  float* S0  = ws + 8 * F;            // [8,10)
  float* S1  = ws + 10 * F;           // [10,12)
  us* XA     = (us*)(ws + 12 * F);    // [12,14)
  us* XB     = (us*)(ws + 14 * F);    // [14,16)
  us* XT     = (us*)(ws + 16 * F);    // [16,18)
  us* Ab     = (us*)(ws + 18 * F);    // [18,19)
  float* SCR = ws + 19 * F;           // [19,20)
  us* W0bT   = (us*)(ws + 20 * F);    // [20,21)
  us* W1bT   = (us*)(ws + 21 * F);    // [21,22)
  us* W1b    = (us*)(ws + 22 * F);    // [22,23)
  us* WmoT   = (us*)(ws + 23 * F);    // [23,23.25)
  us* retrv  = (us*)(ws + 23 * F + 262144);
  float* smal = ws + 23 * F + 262144 + 524288;
  float* og   = smal;
  float* lrv  = og + 2048;
  float* momv = lrv + 2048;
  float* decv = momv + 2048;
  float* cpb  = decv + 2048;
  float* w0inv = cpb + 128;
  float* w1inv = w0inv + 64;
  float* parts = w1inv + 64;
  float* inv01 = parts + 512;

  us* xb   = XA;
  us* Wkb  = XB;
  us* Wqb  = XB + 1048576;
  us* Wvb  = XB + 2097152;
  us* vlin = XT;
  us* WvexpT = XT + 1048576;
  us* Woutb = Ab;
  float* lin = SCR;
  us* Bb = (us*)SCR;
  us* hab   = (us*)SCR;
  float* gp = SCR + 131072;
  us* pr    = (us*)(SCR + 262144);
  float* dh = SCR + 327680;
  us* dhT   = (us*)(SCR + 458752);
  us* rbwT  = (us*)(SCR + 524288);

  const float NSa = 3.4445f, NSb = -4.7750f, NSc = 2.0315f;

  hipMemcpyAsync(W0, Wmem0, (size_t)BIG * 4, hipMemcpyDeviceToDevice, stream);
  hipMemcpyAsync(W1, Wmem1, (size_t)BIG * 4, hipMemcpyDeviceToDevice, stream);
  hipMemsetAsync(S0, 0, (size_t)BIG * 4, stream);
  hipMemsetAsync(S1, 0, (size_t)BIG * 4, stream);
  hipLaunchKernelGGL(tconv_k, dim3(64, 32), dim3(32, 8), 0, stream, Wmem0, W0bT, 1024, 2048);
  hipLaunchKernelGGL(conv_k, dim3(1024), dim3(256), 0, stream, Wmem1, W1b, (int)BIG);
  hipLaunchKernelGGL(tconv_k, dim3(32, 64), dim3(32, 8), 0, stream, Wmem1, W1bT, 2048, 1024);
  hipLaunchKernelGGL(tconv_k, dim3(16, 32), dim3(32, 8), 0, stream, Wmemout, WmoT, 1024, 512);
  hipLaunchKernelGGL(tconv_k, dim3(32, 16), dim3(32, 8), 0, stream, Wvexp, WvexpT, 512, 1024);
  hipLaunchKernelGGL(conv_k, dim3(2048), dim3(256), 0, stream, x, xb, 2048 * 2048);
  hipLaunchKernelGGL(conv_k, dim3(512), dim3(256), 0, stream, Wk, Wkb, 512 * 2048);
  hipLaunchKernelGGL(conv_k, dim3(512), dim3(256), 0, stream, Wq, Wqb, 512 * 2048);
  hipLaunchKernelGGL(conv_k, dim3(512), dim3(256), 0, stream, Wv, Wvb, 512 * 2048);

  mg<7>(stream, xb, nullptr, Wkb, lin, nullptr, nullptr, nullptr, nullptr, nullptr, 0,
        2048, 512, 2048, 2048, 2048, 512, 0, 0.f, 0.f, 0, 0, 0, 0, 1);
  hipLaunchKernelGGL(polynorm2_k, dim3(2048), dim3(256), 0, stream, lin, kp_b);
  mg<7>(stream, xb, nullptr, Wqb, lin, nullptr, nullptr, nullptr, nullptr, nullptr, 0,
        2048, 512, 2048, 2048, 2048, 512, 0, 0.f, 0.f, 0, 0, 0, 0, 1);
  hipLaunchKernelGGL(polynorm2_k, dim3(2048), dim3(256), 0, stream, lin, qp_b);
  mg<5>(stream, xb, nullptr, Wvb, vlin, nullptr, nullptr, nullptr, nullptr, nullptr, 0,
        2048, 512, 2048, 2048, 2048, 512, 0, 0.f, 0.f, 0, 0, 0, 0, 1);
  mg<17>(stream, vlin, nullptr, WvexpT, vexp, nullptr, nullptr, nullptr, nullptr, nullptr, 0,
         2048, 1024, 512, 512, 512, 1024, 0, 0.f, 0.f, 0, 0, 0, 0, 1);

  hipLaunchKernelGGL(gates_k, dim3(2048), dim3(256), 0, stream, x,
                     w_lr, b_lr, w_mom, b_mom, w_dec, b_dec, w_gate, b_gate,
                     lrv, momv, decv, og);
  hipLaunchKernelGGL(chunk_means_k, dim3(32), dim3(64), 0, stream, lrv, momv, decv, cpb);

  for (int c = 0; c < 32; ++c) {
    const us* kp_c = kp_b + (size_t)c * 64 * 1024;
    const us* qp_c = qp_b + (size_t)c * 64 * 1024;
    const float* vexp_c = vexp + (size_t)c * 64 * 1024;
    mg<8, 0, 1>(stream, qp_c, kp_c, W0bT, hab, gp, nullptr, nullptr, nullptr, nullptr, 0,
                128, 2048, 1024, 1024, 1024, 2048, 0, 0.f, 0.f, 0, 0, 0, 0, 1);
    mg<9>(stream, hab, nullptr, W1bT, pr, nullptr, vexp_c, nullptr, nullptr, nullptr, 0,
          128, 1024, 2048, 2048, 2048, 1024, 1024, 0.f, 0.f, 0, 0, 0, 0, 1);
    mg<5>(stream, pr, nullptr, WmoT, retrv + (size_t)c * 64 * 512, nullptr, nullptr,
          nullptr, nullptr, nullptr, 0,
          64, 512, 1024, 1024, 1024, 512, 0, 0.f, 0.f, 0, 0, 0, 0, 1);
    mg<13>(stream, pr + 64 * 1024, nullptr, W1b, dh, nullptr, gp, nullptr, nullptr, nullptr, 0,
           64, 2048, 1024, 1024, 1024, 2048, 2048, 0.f, 0.f, 0, 0, 0, 0, 1);
    hipLaunchKernelGGL(sampnorm2_k, dim3(64), dim3(256), 0, stream,
                       kp_b, dh, hab, pr, w0inv, w1inv, c);
    hipLaunchKernelGGL((wtrans_k<1>), dim3(64, 2), dim3(32, 8), 0, stream, dh, w0inv, dhT, 2048, 2048);
    hipLaunchKernelGGL((wtrans_k<0>), dim3(32, 2), dim3(32, 8), 0, stream, pr + 64 * 1024, w1inv,
                       rbwT, 1024, 1024);
    mg<14, 1>(stream, kp_c, nullptr, dhT, S0, nullptr, nullptr, nullptr, nullptr, cpb, c,
              1024, 2048, 64, 1024, 64, 2048, 0, 0.f, 0.f, 0, 0, 0, 0, 1);
    mg<14, 1>(stream, hab + 64 * 2048, nullptr, rbwT, S1, nullptr, nullptr, nullptr, nullptr, cpb, c,
              2048, 1024, 64, 2048, 64, 1024, 0, 0.f, 0.f, 0, 0, 0, 0, 1);

    // ---- batched NS5: batch0 = S0 (1024x2048), batch1 = S1^T ----
    hipLaunchKernelGGL(frob2_k, dim3(256, 1, 2), dim3(256), 0, stream, S0, S1, (int)BIG, parts);
    hipLaunchKernelGGL(frob_fin2_k, dim3(2), dim3(256), 0, stream, parts, inv01);
    hipLaunchKernelGGL(scale_dual_k, dim3(64, 32), dim3(32, 8), 0, stream,
                       S0, XA, XT, inv01, 1024, 2048);
    hipLaunchKernelGGL(scale_dual_k, dim3(32, 64), dim3(32, 8), 0, stream,
                       S1, XT + SB2, XA + SB2, inv01 + 1, 2048, 1024);

    us* Xc = XA;
    us* Xn = XB;
    for (int it = 0; it < 5; ++it) {
      us* P = Xn;  // dead until BX writes it; holds split-K partials [b][s]
      // XX^T (split-K=2): P[b*2+s] = Xc_b @ Xc_b^T over K-half s
      nsg<2, 0>(stream, Xc, Xc, P, nullptr, 1024, 1024, 2048, 2048, 2048, 1024, 0,
                0.f, 0.f, SB2, SB2, SB1, 0, 2);
      hipLaunchKernelGGL(combA_k, dim3(1024), dim3(256), 0, stream,
                         (const u16x8*)P, (u16x8*)Ab);
      // AA (split-K=2): P[b*2+s] = Ab_b @ Ab_b over K-half s
      nsg<2, 0>(stream, Ab, Ab, P, nullptr, 1024, 1024, 1024, 1024, 1024, 1024, 0,
                0.f, 0.f, SB1, SB1, SB1, 0, 2);
      hipLaunchKernelGGL(combB_k, dim3(1024), dim3(256), 0, stream,
                         (const u16x8*)P, (const u16x8*)Ab, (u16x8*)Bb, NSb, NSc);
      // Xn = Bb@Xc + NSa*Xc   (B operand = XT = Xc^T)
      nsg<1, 6>(stream, Bb, XT, Xn, Xc, 1024, 2048, 1024, 1024, 1024, 2048, 2048,
                1.0f, NSa, SB1, SB2, SB2, SB2, 2);
      if (it < 4)
        hipLaunchKernelGGL(tbf_k, dim3(64, 32, 2), dim3(32, 8), 0, stream, Xn, XT);
      us* tmp = Xc; Xc = Xn; Xn = tmp;
    }
    hipLaunchKernelGGL(wupd0_k, dim3(64, 32), dim3(32, 8), 0, stream, W0, Xc, W0bT, cpb, c);
    hipLaunchKernelGGL(wupd1_k, dim3(64, 32), dim3(32, 8), 0, stream, W1, Xc + SB2, W1b, W1bT, cpb, c);
  }

  hipLaunchKernelGGL(conv_k, dim3(1024), dim3(256), 0, stream, Wout, Woutb, 2048 * 512);
  mg<15, 0, 0, 1>(stream, retrv, nullptr, Woutb, out, nullptr, nullptr, x, og, nullptr, 0,
                  2048, 2048, 512, 512, 512, 2048, 0, 0.f, 0.f, 0, 0, 0, 0, 1);
}